// Round 10
// baseline (183.759 us; speedup 1.0000x reference)
//
#include <hip/hip_runtime.h>

// SimCLR fused pipeline, round 10.
// sim: NSPLIT 64 (2048 blocks = 8/CU) — grid was the occupancy limiter at
//      VGPR 84 (6 waves/SIMD allowed, only 16/CU resident). Same B traffic.
// gemm1: 64-row blocks, grid (128,8) = 4096 waves (2x) for latency hiding.
// gemm2/convert/row_finalize: unchanged (r9-proven).

#define NB   4096
#define DIN  192
#define DHID 512
#define DOUT 128
#define N2   8192   // 2*NB
#define NSPLIT 64   // sim col-splits; 128 cols per block
#define SIM_ITERS (N2 / NSPLIT / 16)   // 8

typedef short short8 __attribute__((ext_vector_type(8)));   // 8 bf16 (4 VGPRs)
typedef float floatx4 __attribute__((ext_vector_type(4)));  // MFMA C/D frag

__device__ inline float fast_exp2(float x) {
#if __has_builtin(__builtin_amdgcn_exp2f)
    return __builtin_amdgcn_exp2f(x);
#else
    return exp2f(x);
#endif
}

__device__ inline unsigned short bf16_rne(float x) {
    unsigned int u = __float_as_uint(x);
    return (unsigned short)((u + 0x7fffu + ((u >> 16) & 1u)) >> 16);
}

// ---------------- convert W1, W2 -> bf16 ------------------------------------
__global__ __launch_bounds__(256) void convert_w(
    const float* __restrict__ W1, const float* __restrict__ W2,
    unsigned short* __restrict__ W1b, unsigned short* __restrict__ W2b)
{
    const int NW1 = DHID * DIN / 4;   // 24576 float4
    const int NW2 = DOUT * DHID / 4;  // 16384 float4
    int id = blockIdx.x * 256 + threadIdx.x;
    const float* src; unsigned short* dst; int off;
    if (id < NW1)            { src = W1; dst = W1b; off = id; }
    else if (id < NW1 + NW2) { src = W2; dst = W2b; off = id - NW1; }
    else return;
    float4 x = ((const float4*)src)[off];
    unsigned int p0 = bf16_rne(x.x) | ((unsigned int)bf16_rne(x.y) << 16);
    unsigned int p1 = bf16_rne(x.z) | ((unsigned int)bf16_rne(x.w) << 16);
    ((uint2*)dst)[off] = make_uint2(p0, p1);
}

// ------- GEMM1 (bf16 MFMA): Y = [h1;h2] @ W1^T + b1, fused BN col-sums -----
// grid (128 m-blocks of 64 rows, 8 n-splits of 64 cols), 256 thr (4 waves).
// Wave: 16 rows x 64 cols (4 nt), K=192 (6 kc).
__global__ __launch_bounds__(256) void gemm1_mfma(
    const float* __restrict__ h1, const float* __restrict__ h2,
    const unsigned short* __restrict__ W1b, const float* __restrict__ b1,
    float* __restrict__ Y, float* __restrict__ psumc, float* __restrict__ psqc)
{
    const int t = threadIdx.x;
    const int wave = t >> 6, lane = t & 63;
    const int quad = lane >> 4, l15 = lane & 15;
    const int mb = blockIdx.x;
    const int m0 = mb * 64 + wave * 16;
    const int n0 = blockIdx.y * 64;
    const int v  = (mb >= 64);

    short8 a[6];
    {
        int row = m0 + l15;
        const float* hsrc = (row < NB) ? (h1 + (size_t)row * DIN)
                                       : (h2 + (size_t)(row - NB) * DIN);
        #pragma unroll
        for (int kc = 0; kc < 6; ++kc) {
            const float4* p = (const float4*)(hsrc + kc * 32 + quad * 8);
            float4 x0 = p[0], x1 = p[1];
            float xs[8] = {x0.x,x0.y,x0.z,x0.w,x1.x,x1.y,x1.z,x1.w};
            #pragma unroll
            for (int j = 0; j < 8; ++j) a[kc][j] = (short)bf16_rne(xs[j]);
        }
    }

    #pragma unroll
    for (int nt = 0; nt < 4; ++nt) {
        const int col = n0 + nt * 16 + l15;
        const short8* bptr = (const short8*)(W1b + (size_t)col * DIN + quad * 8);
        short8 b[6];
        #pragma unroll
        for (int kc = 0; kc < 6; ++kc) b[kc] = bptr[kc * 4];
        floatx4 acc = {0.f,0.f,0.f,0.f};
        #pragma unroll
        for (int kc = 0; kc < 6; ++kc)
            acc = __builtin_amdgcn_mfma_f32_16x16x32_bf16(a[kc], b[kc], acc, 0,0,0);
        const float bias = b1[col];
        float cs = 0.f, cq = 0.f;
        #pragma unroll
        for (int reg = 0; reg < 4; ++reg) {
            float y = acc[reg] + bias;
            int row = m0 + quad * 4 + reg;
            Y[(size_t)row * DHID + col] = y;
            cs += y; cq += y * y;
        }
        cs += __shfl_xor(cs, 16); cs += __shfl_xor(cs, 32);
        cq += __shfl_xor(cq, 16); cq += __shfl_xor(cq, 32);
        if (quad == 0) {
            atomicAdd(psumc + v * DHID + col, cs);
            atomicAdd(psqc  + v * DHID + col, cq);
        }
    }
}

#define ZSCALE 1.6986436f   // sqrt(2*log2(e)); Zb = z*ZSCALE so dot = exp2 arg

// ---- GEMM2 (bf16 MFMA): z = relu(bn(Y)) @ W2^T + b2, L2-norm --------------
// Block: 16 rows x 128 cols, 4 waves (wave w = cols w*32..+31, 2 nt).
// bn-finalize fused in prologue (LDS). 4-wave sq combine via LDS.
// grid 512 x 256 thr.
__global__ __launch_bounds__(256) void gemm2_mfma(
    const float* __restrict__ Y, const unsigned short* __restrict__ W2b,
    const float* __restrict__ psumc, const float* __restrict__ psqc,
    const float* __restrict__ gamma, const float* __restrict__ beta,
    const float* __restrict__ b2,
    unsigned short* __restrict__ Zb, float* __restrict__ outz)
{
    __shared__ float sc_sh[DHID], sh_sh[DHID];
    __shared__ float sq_lds[4][16];
    const int t = threadIdx.x;
    const int wave = t >> 6, lane = t & 63;
    const int quad = lane >> 4, l15 = lane & 15;
    const int mtbase = blockIdx.x * 16;
    const int v = (mtbase >= NB);

    for (int c = t; c < DHID; c += 256) {
        float mean = psumc[v * DHID + c] * (1.0f / NB);
        float var  = psqc [v * DHID + c] * (1.0f / NB) - mean * mean;
        float rstd = rsqrtf(var + 1e-5f);
        float scv = gamma[c] * rstd;
        sc_sh[c] = scv;
        sh_sh[c] = beta[c] - mean * scv;
    }
    __syncthreads();

    const float* yrow = Y + (size_t)(mtbase + l15) * DHID;
    floatx4 acc[2] = {{0.f,0.f,0.f,0.f},{0.f,0.f,0.f,0.f}};
    for (int kc = 0; kc < 16; ++kc) {
        const int k = kc * 32 + quad * 8;
        float4 y0 = *(const float4*)(yrow + k);
        float4 y1 = *(const float4*)(yrow + k + 4);
        float4 s0 = *(const float4*)&sc_sh[k], s1 = *(const float4*)&sc_sh[k + 4];
        float4 h0 = *(const float4*)&sh_sh[k], h1v = *(const float4*)&sh_sh[k + 4];
        float xs[8];
        xs[0] = fmaxf(y0.x * s0.x + h0.x, 0.f);
        xs[1] = fmaxf(y0.y * s0.y + h0.y, 0.f);
        xs[2] = fmaxf(y0.z * s0.z + h0.z, 0.f);
        xs[3] = fmaxf(y0.w * s0.w + h0.w, 0.f);
        xs[4] = fmaxf(y1.x * s1.x + h1v.x, 0.f);
        xs[5] = fmaxf(y1.y * s1.y + h1v.y, 0.f);
        xs[6] = fmaxf(y1.z * s1.z + h1v.z, 0.f);
        xs[7] = fmaxf(y1.w * s1.w + h1v.w, 0.f);
        short8 a;
        #pragma unroll
        for (int j = 0; j < 8; ++j) a[j] = (short)bf16_rne(xs[j]);
        #pragma unroll
        for (int nt = 0; nt < 2; ++nt) {
            const int col = wave * 32 + nt * 16 + l15;
            short8 b = *(const short8*)(W2b + (size_t)col * DHID + k);
            acc[nt] = __builtin_amdgcn_mfma_f32_16x16x32_bf16(a, b, acc[nt], 0,0,0);
        }
    }
    float bias[2];
    #pragma unroll
    for (int nt = 0; nt < 2; ++nt) bias[nt] = b2[wave * 32 + nt * 16 + l15];

    float zv[4][2];
    #pragma unroll
    for (int reg = 0; reg < 4; ++reg) {
        float sq = 0.f;
        #pragma unroll
        for (int nt = 0; nt < 2; ++nt) {
            zv[reg][nt] = acc[nt][reg] + bias[nt];
            sq += zv[reg][nt] * zv[reg][nt];
        }
        sq += __shfl_xor(sq, 1); sq += __shfl_xor(sq, 2);
        sq += __shfl_xor(sq, 4); sq += __shfl_xor(sq, 8);
        if (l15 == 0) sq_lds[wave][quad * 4 + reg] = sq;
    }
    __syncthreads();
    #pragma unroll
    for (int reg = 0; reg < 4; ++reg) {
        float tot = sq_lds[0][quad * 4 + reg] + sq_lds[1][quad * 4 + reg]
                  + sq_lds[2][quad * 4 + reg] + sq_lds[3][quad * 4 + reg];
        float inv = 1.0f / fmaxf(sqrtf(tot), 1e-12f);
        const int row = mtbase + quad * 4 + reg;
        const size_t ob = (size_t)row * DOUT;
        #pragma unroll
        for (int nt = 0; nt < 2; ++nt) {
            const int col = wave * 32 + nt * 16 + l15;
            float z = zv[reg][nt] * inv;
            outz[ob + col] = z;
            Zb[ob + col] = bf16_rne(z * ZSCALE);
        }
    }
}

// ---- sim: psum_row = sum_cols exp2(Zb . Zb^T)  (diag included; subtracted
// in row_finalize). Wave owns 64 rows (4 A-tiles in regs); dynamic loop,
// dist-1 double-buffered 16-col B-tile; 16 MFMA + 16 exp per iter.
// grid (32, NSPLIT=64) = 2048 blocks (8/CU) x 256 thr.
__global__ __launch_bounds__(256) void sim_mfma(
    const unsigned short* __restrict__ Zb, float* __restrict__ psum)
{
    const int t = threadIdx.x;
    const int wave = t >> 6, lane = t & 63;
    const int quad = lane >> 4, l15 = lane & 15;
    const int mbase = blockIdx.x * 256 + wave * 64;   // 64 rows per wave
    const int cs = blockIdx.y;                        // 0..NSPLIT-1
    const int cbase = cs * (N2 / NSPLIT);             // 128-col slice

    short8 a[4][4];
    #pragma unroll
    for (int at = 0; at < 4; ++at) {
        const short8* zra = (const short8*)(Zb + (size_t)(mbase + at * 16 + l15) * DOUT + quad * 8);
        #pragma unroll
        for (int kc = 0; kc < 4; ++kc) a[at][kc] = zra[kc * 4];
    }

    float rs[4][4];
    #pragma unroll
    for (int at = 0; at < 4; ++at)
        #pragma unroll
        for (int r = 0; r < 4; ++r) rs[at][r] = 0.f;

    short8 bcur[4], bnext[4];
    {
        const short8* zb = (const short8*)(Zb + (size_t)(cbase + l15) * DOUT + quad * 8);
        #pragma unroll
        for (int kc = 0; kc < 4; ++kc) bcur[kc] = zb[kc * 4];
    }

    for (int nt = 0; nt < SIM_ITERS; ++nt) {
        const int cn = cbase + ((nt + 1) & (SIM_ITERS - 1)) * 16;
        const short8* zbn = (const short8*)(Zb + (size_t)(cn + l15) * DOUT + quad * 8);
        #pragma unroll
        for (int kc = 0; kc < 4; ++kc) bnext[kc] = zbn[kc * 4];

        floatx4 acc[4] = {{0.f,0.f,0.f,0.f},{0.f,0.f,0.f,0.f},
                          {0.f,0.f,0.f,0.f},{0.f,0.f,0.f,0.f}};
        #pragma unroll
        for (int kc = 0; kc < 4; ++kc)
            #pragma unroll
            for (int at = 0; at < 4; ++at)
                acc[at] = __builtin_amdgcn_mfma_f32_16x16x32_bf16(a[at][kc], bcur[kc], acc[at], 0, 0, 0);

        #pragma unroll
        for (int at = 0; at < 4; ++at)
            #pragma unroll
            for (int r = 0; r < 4; ++r)
                rs[at][r] += fast_exp2(acc[at][r]);

        #pragma unroll
        for (int kc = 0; kc < 4; ++kc) bcur[kc] = bnext[kc];
    }

    #pragma unroll
    for (int at = 0; at < 4; ++at) {
        const int gi0 = mbase + at * 16 + quad * 4;
        #pragma unroll
        for (int r = 0; r < 4; ++r) {
            float s = rs[at][r];
            s += __shfl_xor(s, 1);
            s += __shfl_xor(s, 2);
            s += __shfl_xor(s, 4);
            s += __shfl_xor(s, 8);
            if (l15 == 0) psum[(size_t)cs * N2 + gi0 + r] = s;
        }
    }
}

// ---- per-row lse - pos, minus diag term; block-reduce -> atomic loss ------
__global__ __launch_bounds__(256) void row_finalize(
    const unsigned short* __restrict__ Zb, const float* __restrict__ psum,
    float* __restrict__ out)
{
    int i = blockIdx.x * 256 + threadIdx.x;
    float s = 0.f;
    for (int cs = 0; cs < NSPLIT; ++cs) s += psum[(size_t)cs * N2 + i];
    int k = i & (NB - 1);
    const uint4* z1 = (const uint4*)(Zb + (size_t)k * DOUT);
    const uint4* z2 = (const uint4*)(Zb + (size_t)(k + NB) * DOUT);
    float d12 = 0.f, d11 = 0.f, d22 = 0.f;
    #pragma unroll
    for (int q = 0; q < 16; ++q) {
        uint4 a = z1[q], bqq = z2[q];
        const unsigned int aw[4] = {a.x, a.y, a.z, a.w};
        const unsigned int bw[4] = {bqq.x, bqq.y, bqq.z, bqq.w};
        #pragma unroll
        for (int c = 0; c < 4; ++c) {
            float alo = __uint_as_float(aw[c] << 16);
            float ahi = __uint_as_float(aw[c] & 0xffff0000u);
            float blo = __uint_as_float(bw[c] << 16);
            float bhi = __uint_as_float(bw[c] & 0xffff0000u);
            d12 += alo * blo + ahi * bhi;
            d11 += alo * alo + ahi * ahi;
            d22 += blo * blo + bhi * bhi;
        }
    }
    float dself = (i < NB) ? d11 : d22;
    // Zb is scaled: dot' = 2*log2(e)*dot => 2*dot = dot'*ln2; diag = exp2(dot')
    float rowval = logf(s - fast_exp2(dself)) - d12 * 0.69314718f;

    float r = rowval;
    r += __shfl_xor(r, 1);  r += __shfl_xor(r, 2);  r += __shfl_xor(r, 4);
    r += __shfl_xor(r, 8);  r += __shfl_xor(r, 16); r += __shfl_xor(r, 32);
    __shared__ float wsr[4];
    int lane = threadIdx.x & 63, w = threadIdx.x >> 6;
    if (lane == 0) wsr[w] = r;
    __syncthreads();
    if (threadIdx.x == 0)
        atomicAdd(out, (wsr[0] + wsr[1] + wsr[2] + wsr[3]) * (1.0f / N2));
}

extern "C" void kernel_launch(void* const* d_in, const int* in_sizes, int n_in,
                              void* d_out, int out_size, void* d_ws, size_t ws_size,
                              hipStream_t stream)
{
    const float* h1    = (const float*)d_in[0];
    const float* h2    = (const float*)d_in[1];
    const float* W1    = (const float*)d_in[2];
    const float* b1    = (const float*)d_in[3];
    const float* gamma = (const float*)d_in[4];
    const float* beta  = (const float*)d_in[5];
    const float* W2    = (const float*)d_in[6];
    const float* b2    = (const float*)d_in[7];
    float* out = (float*)d_out;

    float* ws      = (float*)d_ws;
    float* psumc   = ws;                            // 1024 f
    float* psqc    = psumc + 1024;                  // 1024 f
    unsigned short* W1b = (unsigned short*)(psqc + 1024);   // 98304 us
    unsigned short* W2b = W1b + DHID * DIN;         // 65536 us
    float* Y       = (float*)(W2b + DOUT * DHID);   // 8192*512 = 4M f
    float* psum    = Y + (size_t)N2 * DHID;         // 64*8192 f = 2MB
    unsigned short* Zb = (unsigned short*)(psum + (size_t)NSPLIT * N2); // 1M us
    // total ~21.3 MB

    hipMemsetAsync(psumc, 0, 2048 * sizeof(float), stream);  // psumc+psqc
    hipMemsetAsync(out, 0, sizeof(float), stream);           // loss accumulator

    convert_w   <<<dim3(160),        256, 0, stream>>>(W1, W2, W1b, W2b);
    gemm1_mfma  <<<dim3(128, 8),     256, 0, stream>>>(h1, h2, W1b, b1, Y, psumc, psqc);
    gemm2_mfma  <<<dim3(512),        256, 0, stream>>>(Y, W2b, psumc, psqc, gamma, beta, b2, Zb, out + 1);
    sim_mfma    <<<dim3(32, NSPLIT), 256, 0, stream>>>(Zb, psum);
    row_finalize<<<dim3(32),         256, 0, stream>>>(Zb, psum, out);
}

// Round 11
// 166.294 us; speedup vs baseline: 1.1050x; 1.1050x over previous
//
#include <hip/hip_runtime.h>

// SimCLR fused pipeline, round 11.
// sim: exact r9 config (NSPLIT 32 -> rolled 16-iter loop, VGPR 84). r10's
//      NSPLIT=64 made the compiler fully unroll (VGPR 128, -27%).
// gemm2: rebuilt on the sim-proven lean pattern: 8 waves x (16r x 16c),
//      4096 waves (4/SIMD), dist-1 prefetch of Y+W2 tiles, rolled loop.
// Y now bf16 (half the IO); h pre-converted to bf16 once in convert_w.

#define NB   4096
#define DIN  192
#define DHID 512
#define DOUT 128
#define N2   8192   // 2*NB
#define NSPLIT 32   // sim col-splits; 256 cols per block
#define SIM_ITERS 16

typedef short short8 __attribute__((ext_vector_type(8)));   // 8 bf16 (4 VGPRs)
typedef float floatx4 __attribute__((ext_vector_type(4)));  // MFMA C/D frag

__device__ inline float fast_exp2(float x) {
#if __has_builtin(__builtin_amdgcn_exp2f)
    return __builtin_amdgcn_exp2f(x);
#else
    return exp2f(x);
#endif
}

__device__ inline unsigned short bf16_rne(float x) {
    unsigned int u = __float_as_uint(x);
    return (unsigned short)((u + 0x7fffu + ((u >> 16) & 1u)) >> 16);
}

// ---------- convert W1, W2, h1, h2 -> bf16 ---------------------------------
#define NW1 (DHID * DIN / 4)    // 24576 float4
#define NW2 (DOUT * DHID / 4)   // 16384 float4
#define NH  (NB * DIN / 4)      // 196608 float4 (per view)
__global__ __launch_bounds__(256) void convert_w(
    const float* __restrict__ W1, const float* __restrict__ W2,
    const float* __restrict__ h1, const float* __restrict__ h2,
    unsigned short* __restrict__ W1b, unsigned short* __restrict__ W2b,
    unsigned short* __restrict__ Hb)
{
    int id = blockIdx.x * 256 + threadIdx.x;
    const float* src; unsigned short* dst; int off;
    if (id < NW1)                 { src = W1; dst = W1b; off = id; }
    else if (id < NW1 + NW2)      { src = W2; dst = W2b; off = id - NW1; }
    else if (id < NW1 + NW2 + NH) { src = h1; dst = Hb;  off = id - NW1 - NW2; }
    else if (id < NW1 + NW2 + 2 * NH) {
        src = h2; dst = Hb + (size_t)NB * DIN; off = id - NW1 - NW2 - NH;
    } else return;
    float4 x = ((const float4*)src)[off];
    unsigned int p0 = bf16_rne(x.x) | ((unsigned int)bf16_rne(x.y) << 16);
    unsigned int p1 = bf16_rne(x.z) | ((unsigned int)bf16_rne(x.w) << 16);
    ((uint2*)dst)[off] = make_uint2(p0, p1);
}

// ------- GEMM1 (bf16 MFMA): Ybf = [h1;h2] @ W1^T + b1, fused BN col-sums ---
// grid (128 m-blocks of 64 rows, 8 n-splits of 64 cols), 256 thr (4 waves).
// Wave: 16 rows x 64 cols (4 nt), K=192 (6 kc). A from pre-converted Hb.
__global__ __launch_bounds__(256) void gemm1_mfma(
    const unsigned short* __restrict__ Hb,
    const unsigned short* __restrict__ W1b, const float* __restrict__ b1,
    unsigned short* __restrict__ Ybf,
    float* __restrict__ psumc, float* __restrict__ psqc)
{
    const int t = threadIdx.x;
    const int wave = t >> 6, lane = t & 63;
    const int quad = lane >> 4, l15 = lane & 15;
    const int mb = blockIdx.x;
    const int m0 = mb * 64 + wave * 16;
    const int n0 = blockIdx.y * 64;
    const int v  = (mb >= 64);

    short8 a[6];
    {
        const short8* ap = (const short8*)(Hb + (size_t)(m0 + l15) * DIN + quad * 8);
        #pragma unroll
        for (int kc = 0; kc < 6; ++kc) a[kc] = ap[kc * 4];
    }

    #pragma unroll
    for (int nt = 0; nt < 4; ++nt) {
        const int col = n0 + nt * 16 + l15;
        const short8* bptr = (const short8*)(W1b + (size_t)col * DIN + quad * 8);
        short8 b[6];
        #pragma unroll
        for (int kc = 0; kc < 6; ++kc) b[kc] = bptr[kc * 4];
        floatx4 acc = {0.f,0.f,0.f,0.f};
        #pragma unroll
        for (int kc = 0; kc < 6; ++kc)
            acc = __builtin_amdgcn_mfma_f32_16x16x32_bf16(a[kc], b[kc], acc, 0,0,0);
        const float bias = b1[col];
        float cs = 0.f, cq = 0.f;
        #pragma unroll
        for (int reg = 0; reg < 4; ++reg) {
            float y = acc[reg] + bias;
            int row = m0 + quad * 4 + reg;
            Ybf[(size_t)row * DHID + col] = bf16_rne(y);
            cs += y; cq += y * y;
        }
        cs += __shfl_xor(cs, 16); cs += __shfl_xor(cs, 32);
        cq += __shfl_xor(cq, 16); cq += __shfl_xor(cq, 32);
        if (quad == 0) {
            atomicAdd(psumc + v * DHID + col, cs);
            atomicAdd(psqc  + v * DHID + col, cq);
        }
    }
}

#define ZSCALE 1.6986436f   // sqrt(2*log2(e)); Zb = z*ZSCALE so dot = exp2 arg

// ---- GEMM2 (bf16 MFMA): z = relu(bn(Y)) @ W2^T + b2, L2-norm --------------
// 8 waves x (16 rows x 16 cols), grid 512 x 512 thr = 4096 waves (4/SIMD).
// Rolled 16-iter K-loop with dist-1 prefetch of Y (1 uint4) and W2 (1 short8).
// bn-finalize fused in prologue; 8-wave sq combine via LDS.
__global__ __launch_bounds__(512) void gemm2_mfma(
    const unsigned short* __restrict__ Ybf, const unsigned short* __restrict__ W2b,
    const float* __restrict__ psumc, const float* __restrict__ psqc,
    const float* __restrict__ gamma, const float* __restrict__ beta,
    const float* __restrict__ b2,
    unsigned short* __restrict__ Zb, float* __restrict__ outz)
{
    __shared__ float sc_sh[DHID], sh_sh[DHID];
    __shared__ float sq_lds[8][16];
    const int t = threadIdx.x;
    const int wave = t >> 6, lane = t & 63;
    const int quad = lane >> 4, l15 = lane & 15;
    const int mtbase = blockIdx.x * 16;
    const int v = (mtbase >= NB);
    const int col = wave * 16 + l15;

    {   // bn finalize: 512 threads cover 512 cols
        int c = t;
        float mean = psumc[v * DHID + c] * (1.0f / NB);
        float var  = psqc [v * DHID + c] * (1.0f / NB) - mean * mean;
        float rstd = rsqrtf(var + 1e-5f);
        float scv = gamma[c] * rstd;
        sc_sh[c] = scv;
        sh_sh[c] = beta[c] - mean * scv;
    }
    __syncthreads();

    const unsigned short* yrow = Ybf + (size_t)(mtbase + l15) * DHID + quad * 8;
    const unsigned short* wcol = W2b + (size_t)col * DHID + quad * 8;

    uint4 ycur = *(const uint4*)yrow;
    short8 bcur = *(const short8*)wcol;
    floatx4 acc = {0.f, 0.f, 0.f, 0.f};

    for (int kc = 0; kc < 16; ++kc) {
        uint4 ynext; short8 bnext;
        const int kn = (kc + 1) & 15;         // wraps on last iter (unused)
        ynext = *(const uint4*)(yrow + kn * 32);
        bnext = *(const short8*)(wcol + kn * 32);

        const int k = kc * 32 + quad * 8;
        const float4 s0 = *(const float4*)&sc_sh[k], s1 = *(const float4*)&sc_sh[k + 4];
        const float4 h0 = *(const float4*)&sh_sh[k], h1v = *(const float4*)&sh_sh[k + 4];
        const unsigned int yw[4] = {ycur.x, ycur.y, ycur.z, ycur.w};
        float xs[8];
        #pragma unroll
        for (int c2 = 0; c2 < 4; ++c2) {
            xs[c2 * 2]     = __uint_as_float(yw[c2] << 16);
            xs[c2 * 2 + 1] = __uint_as_float(yw[c2] & 0xffff0000u);
        }
        const float ss[8] = {s0.x,s0.y,s0.z,s0.w,s1.x,s1.y,s1.z,s1.w};
        const float hh[8] = {h0.x,h0.y,h0.z,h0.w,h1v.x,h1v.y,h1v.z,h1v.w};
        short8 afr;
        #pragma unroll
        for (int j = 0; j < 8; ++j)
            afr[j] = (short)bf16_rne(fmaxf(xs[j] * ss[j] + hh[j], 0.f));
        acc = __builtin_amdgcn_mfma_f32_16x16x32_bf16(afr, bcur, acc, 0,0,0);
        ycur = ynext; bcur = bnext;
    }

    const float bias = b2[col];
    float zv[4];
    #pragma unroll
    for (int reg = 0; reg < 4; ++reg) {
        zv[reg] = acc[reg] + bias;
        float q = zv[reg] * zv[reg];
        q += __shfl_xor(q, 1); q += __shfl_xor(q, 2);
        q += __shfl_xor(q, 4); q += __shfl_xor(q, 8);
        if (l15 == 0) sq_lds[wave][quad * 4 + reg] = q;
    }
    __syncthreads();
    #pragma unroll
    for (int reg = 0; reg < 4; ++reg) {
        float tot = 0.f;
        #pragma unroll
        for (int w = 0; w < 8; ++w) tot += sq_lds[w][quad * 4 + reg];
        float inv = 1.0f / fmaxf(sqrtf(tot), 1e-12f);
        const int row = mtbase + quad * 4 + reg;
        float z = zv[reg] * inv;
        outz[(size_t)row * DOUT + col] = z;
        Zb[(size_t)row * DOUT + col] = bf16_rne(z * ZSCALE);
    }
}

// ---- sim: psum_row = sum_cols exp2(Zb . Zb^T)  (diag included; subtracted
// in row_finalize). r9-exact: wave owns 64 rows (4 A-tiles in regs); rolled
// 16-iter loop, dist-1 double-buffered 16-col B-tile; 16 MFMA + 16 exp/iter.
// grid (32, NSPLIT=32) x 256 thr.
__global__ __launch_bounds__(256) void sim_mfma(
    const unsigned short* __restrict__ Zb, float* __restrict__ psum)
{
    const int t = threadIdx.x;
    const int wave = t >> 6, lane = t & 63;
    const int quad = lane >> 4, l15 = lane & 15;
    const int mbase = blockIdx.x * 256 + wave * 64;   // 64 rows per wave
    const int cs = blockIdx.y;                        // 0..NSPLIT-1
    const int cbase = cs * (N2 / NSPLIT);             // 256-col slice

    short8 a[4][4];
    #pragma unroll
    for (int at = 0; at < 4; ++at) {
        const short8* zra = (const short8*)(Zb + (size_t)(mbase + at * 16 + l15) * DOUT + quad * 8);
        #pragma unroll
        for (int kc = 0; kc < 4; ++kc) a[at][kc] = zra[kc * 4];
    }

    float rs[4][4];
    #pragma unroll
    for (int at = 0; at < 4; ++at)
        #pragma unroll
        for (int r = 0; r < 4; ++r) rs[at][r] = 0.f;

    short8 bcur[4], bnext[4];
    {
        const short8* zb = (const short8*)(Zb + (size_t)(cbase + l15) * DOUT + quad * 8);
        #pragma unroll
        for (int kc = 0; kc < 4; ++kc) bcur[kc] = zb[kc * 4];
    }

    for (int nt = 0; nt < SIM_ITERS; ++nt) {
        const int cn = cbase + ((nt + 1) & (SIM_ITERS - 1)) * 16;
        const short8* zbn = (const short8*)(Zb + (size_t)(cn + l15) * DOUT + quad * 8);
        #pragma unroll
        for (int kc = 0; kc < 4; ++kc) bnext[kc] = zbn[kc * 4];

        floatx4 acc[4] = {{0.f,0.f,0.f,0.f},{0.f,0.f,0.f,0.f},
                          {0.f,0.f,0.f,0.f},{0.f,0.f,0.f,0.f}};
        #pragma unroll
        for (int kc = 0; kc < 4; ++kc)
            #pragma unroll
            for (int at = 0; at < 4; ++at)
                acc[at] = __builtin_amdgcn_mfma_f32_16x16x32_bf16(a[at][kc], bcur[kc], acc[at], 0, 0, 0);

        #pragma unroll
        for (int at = 0; at < 4; ++at)
            #pragma unroll
            for (int r = 0; r < 4; ++r)
                rs[at][r] += fast_exp2(acc[at][r]);

        #pragma unroll
        for (int kc = 0; kc < 4; ++kc) bcur[kc] = bnext[kc];
    }

    #pragma unroll
    for (int at = 0; at < 4; ++at) {
        const int gi0 = mbase + at * 16 + quad * 4;
        #pragma unroll
        for (int r = 0; r < 4; ++r) {
            float s = rs[at][r];
            s += __shfl_xor(s, 1);
            s += __shfl_xor(s, 2);
            s += __shfl_xor(s, 4);
            s += __shfl_xor(s, 8);
            if (l15 == 0) psum[(size_t)cs * N2 + gi0 + r] = s;
        }
    }
}

// ---- per-row lse - pos, minus diag term; block-reduce -> atomic loss ------
__global__ __launch_bounds__(256) void row_finalize(
    const unsigned short* __restrict__ Zb, const float* __restrict__ psum,
    float* __restrict__ out)
{
    int i = blockIdx.x * 256 + threadIdx.x;
    float s = 0.f;
    for (int cs = 0; cs < NSPLIT; ++cs) s += psum[(size_t)cs * N2 + i];
    int k = i & (NB - 1);
    const uint4* z1 = (const uint4*)(Zb + (size_t)k * DOUT);
    const uint4* z2 = (const uint4*)(Zb + (size_t)(k + NB) * DOUT);
    float d12 = 0.f, d11 = 0.f, d22 = 0.f;
    #pragma unroll
    for (int q = 0; q < 16; ++q) {
        uint4 a = z1[q], bqq = z2[q];
        const unsigned int aw[4] = {a.x, a.y, a.z, a.w};
        const unsigned int bw[4] = {bqq.x, bqq.y, bqq.z, bqq.w};
        #pragma unroll
        for (int c = 0; c < 4; ++c) {
            float alo = __uint_as_float(aw[c] << 16);
            float ahi = __uint_as_float(aw[c] & 0xffff0000u);
            float blo = __uint_as_float(bw[c] << 16);
            float bhi = __uint_as_float(bw[c] & 0xffff0000u);
            d12 += alo * blo + ahi * bhi;
            d11 += alo * alo + ahi * ahi;
            d22 += blo * blo + bhi * bhi;
        }
    }
    float dself = (i < NB) ? d11 : d22;
    // Zb is scaled: dot' = 2*log2(e)*dot => 2*dot = dot'*ln2; diag = exp2(dot')
    float rowval = logf(s - fast_exp2(dself)) - d12 * 0.69314718f;

    float r = rowval;
    r += __shfl_xor(r, 1);  r += __shfl_xor(r, 2);  r += __shfl_xor(r, 4);
    r += __shfl_xor(r, 8);  r += __shfl_xor(r, 16); r += __shfl_xor(r, 32);
    __shared__ float wsr[4];
    int lane = threadIdx.x & 63, w = threadIdx.x >> 6;
    if (lane == 0) wsr[w] = r;
    __syncthreads();
    if (threadIdx.x == 0)
        atomicAdd(out, (wsr[0] + wsr[1] + wsr[2] + wsr[3]) * (1.0f / N2));
}

extern "C" void kernel_launch(void* const* d_in, const int* in_sizes, int n_in,
                              void* d_out, int out_size, void* d_ws, size_t ws_size,
                              hipStream_t stream)
{
    const float* h1    = (const float*)d_in[0];
    const float* h2    = (const float*)d_in[1];
    const float* W1    = (const float*)d_in[2];
    const float* b1    = (const float*)d_in[3];
    const float* gamma = (const float*)d_in[4];
    const float* beta  = (const float*)d_in[5];
    const float* W2    = (const float*)d_in[6];
    const float* b2    = (const float*)d_in[7];
    float* out = (float*)d_out;

    float* ws      = (float*)d_ws;
    float* psumc   = ws;                            // 1024 f
    float* psqc    = psumc + 1024;                  // 1024 f
    unsigned short* W1b = (unsigned short*)(psqc + 1024);   // 98304 us
    unsigned short* W2b = W1b + DHID * DIN;         // 65536 us
    unsigned short* Hb  = (unsigned short*)(W2b + DOUT * DHID); // 2*4096*192 us = 3MB
    unsigned short* Ybf = Hb + (size_t)N2 * DIN;    // 8192*512 us = 8MB
    float* psum    = (float*)(Ybf + (size_t)N2 * DHID); // 32*8192 f = 1MB
    unsigned short* Zb = (unsigned short*)(psum + (size_t)NSPLIT * N2); // 2MB
    // total ~14.5 MB

    hipMemsetAsync(psumc, 0, 2048 * sizeof(float), stream);  // psumc+psqc
    hipMemsetAsync(out, 0, sizeof(float), stream);           // loss accumulator

    const int conv_blocks = (NW1 + NW2 + 2 * NH + 255) / 256;  // 1698
    convert_w   <<<dim3(conv_blocks),  256, 0, stream>>>(W1, W2, h1, h2, W1b, W2b, Hb);
    gemm1_mfma  <<<dim3(128, 8),       256, 0, stream>>>(Hb, W1b, b1, Ybf, psumc, psqc);
    gemm2_mfma  <<<dim3(512),          512, 0, stream>>>(Ybf, W2b, psumc, psqc, gamma, beta, b2, Zb, out + 1);
    sim_mfma    <<<dim3(32, NSPLIT),   256, 0, stream>>>(Zb, psum);
    row_finalize<<<dim3(32),           256, 0, stream>>>(Zb, psum, out);
}